// Round 25
// baseline (122.825 us; speedup 1.0000x reference)
//
#include <hip/hip_runtime.h>
#include <hip/hip_bf16.h>

#define B_   2
#define T_   2048
#define HID_ 1024
#define NH_  16
#define HD_  64
#define K_   1024
#define M_   (B_*T_)

typedef __attribute__((ext_vector_type(8)))  short bf16x8;
typedef __attribute__((ext_vector_type(4)))  float f32x4;
typedef __attribute__((ext_vector_type(16))) float f32x16;
typedef __attribute__((ext_vector_type(4)))  unsigned int u32x4;
typedef __attribute__((ext_vector_type(2)))  unsigned int u32x2;

#define LOG2E 1.44269504088896340736f

__device__ inline unsigned short f2bf(float f) {
    __hip_bfloat16 h = __float2bfloat16(f);
    return __builtin_bit_cast(unsigned short, h);
}
__device__ inline unsigned int pk2(float a, float b) {
    return (unsigned int)f2bf(a) | ((unsigned int)f2bf(b) << 16);
}
// truncation pack: (a>>16) | (b & 0xffff0000) in ONE v_perm_b32
__device__ inline unsigned int pkt(float a, float b) {
    return __builtin_amdgcn_perm(__builtin_bit_cast(unsigned, a),
                                 __builtin_bit_cast(unsigned, b), 0x03020706u);
}
__device__ inline bf16x8 cvt8(float4 a, float4 b) {
    bf16x8 r;
    r[0]=(short)f2bf(a.x); r[1]=(short)f2bf(a.y); r[2]=(short)f2bf(a.z); r[3]=(short)f2bf(a.w);
    r[4]=(short)f2bf(b.x); r[5]=(short)f2bf(b.y); r[6]=(short)f2bf(b.z); r[7]=(short)f2bf(b.w);
    return r;
}
// async global->LDS, 16 bytes/lane. LDS dest wave-uniform base; HW adds lane*16.
// Global SOURCE is per-lane -> swizzled layouts via pre-swizzled source (rule #21).
__device__ inline void gll16(const void* g, void* l) {
    __builtin_amdgcn_global_load_lds(
        (const __attribute__((address_space(1))) unsigned int*)g,
        (__attribute__((address_space(3))) unsigned int*)l, 16, 0, 0);
}

// ---------------- fp32 -> bf16 cast, single launch (x + 4 weights) ----------------
__global__ __launch_bounds__(256)
void cast_all(const float* __restrict__ x,
              const float* __restrict__ W0, const float* __restrict__ W1,
              const float* __restrict__ W2, const float* __restrict__ W3,
              unsigned short* __restrict__ xo,
              unsigned short* __restrict__ o0, unsigned short* __restrict__ o1,
              unsigned short* __restrict__ o2, unsigned short* __restrict__ o3) {
    const int blk = blockIdx.x;
    const float* in;
    unsigned short* out;
    int i;
    if (blk < 2048) {
        in = x; out = xo; i = blk * 256 + threadIdx.x;
    } else {
        const int wb = blk - 2048, sec = wb >> 9;
        in  = (sec == 0) ? W0 : (sec == 1) ? W1 : (sec == 2) ? W2 : W3;
        out = (sec == 0) ? o0 : (sec == 1) ? o1 : (sec == 2) ? o2 : o3;
        i = (wb & 511) * 256 + threadIdx.x;
    }
    float4 a = ((const float4*)in)[2*i], b = ((const float4*)in)[2*i + 1];
    ((bf16x8*)out)[i] = cvt8(a, b);
}

// ---------------- bf16 GEMM-NT: gload_lds + inverse-swizzled SOURCE (rule #21) ------
// LDS dest linear (HW requirement); per-lane global source col = 8*((l&7)^(row&7))
// so LDS lands in the SAME swizzled layout the proven fragment ds_reads expect.
// 2-phase dbuf: issue STAGE(buf^1,k+64) first, MFMA on buf, ONE barrier (its
// vmcnt(0) drain happens after loads had the whole MFMA phase to fly).
template<int TYPE>
__global__ __launch_bounds__(256)
void gemm_k(const unsigned short* __restrict__ A, const unsigned short* __restrict__ W0,
            const unsigned short* __restrict__ W1, const unsigned short* __restrict__ W2,
            const float* __restrict__ cs, const float* __restrict__ sn,
            unsigned short* __restrict__ qb, unsigned short* __restrict__ kb,
            unsigned short* __restrict__ vtb, float* __restrict__ fout) {
    constexpr int BN    = (TYPE == 1) ? 64 : 128;   // N-tile width
    constexpr int NF    = BN / 32;                  // B fragments per wave
    constexpr int NBSEG = BN / 32;                  // B 8-row segs per wave
    __shared__ unsigned short As[2][128*64];
    __shared__ unsigned short Bs[2][BN*64];
    const int tid = threadIdx.x;
    const int w = tid >> 6, lane = tid & 63;
    const int u = lane >> 4, c = lane & 15;
    const int bid = blockIdx.x;
    const int xcd = bid & 7, idx = bid >> 3;
    int bmi, bni;
    if constexpr (TYPE == 0) {          // 32 x 24 tiles, 8 XCD x (8bm x 12bn)
        bmi = (xcd & 3) * 8 + (idx & 7);
        bni = (xcd >> 2) * 12 + (idx >> 3);
    } else {                            // 32 x 16 tiles, 8 XCD x (8bm x 8bn)
        bmi = (xcd & 3) * 8 + (idx & 7);
        bni = (xcd >> 2) * 8 + (idx >> 3);
    }
    const int bm = bmi * 128, bn = bni * BN;
    const int wm = (w & 1) * 64, wn = (w >> 1) * (BN / 2);

    const unsigned short* Wsec;
    int wrowbase;
    if constexpr (TYPE == 0) {
        const int sec = bn >> 10;
        Wsec = (sec == 0) ? W0 : ((sec == 1) ? W1 : W2);
        wrowbase = bn & 1023;
    } else {
        Wsec = W0;
        wrowbase = bn;
    }
    const unsigned short* Ab = A + (size_t)bm * K_;
    const unsigned short* Wb = Wsec + (size_t)wrowbase * K_;
    // inverse-swizzled per-lane source: row-in-seg = lane>>3, col = 8*((l&7)^(row&7))
    const int lrow8 = lane >> 3;                         // 0..7
    const int scolx = 8 * ((lane & 7) ^ (lrow8 & 7));    // swizzled col (elems)

    f32x4 acc[4][NF] = {};

    auto stage = [&](int buf, int k0) {
        #pragma unroll
        for (int s4 = 0; s4 < 4; ++s4) {
            const int seg = w * 4 + s4;                  // 16 A segs of 8 rows
            gll16(Ab + (size_t)(seg * 8 + lrow8) * K_ + k0 + scolx,
                  (char*)&As[buf][0] + seg * 1024);
        }
        #pragma unroll
        for (int s4 = 0; s4 < NBSEG; ++s4) {
            const int seg = w * NBSEG + s4;              // BN/8 B segs
            gll16(Wb + (size_t)(seg * 8 + lrow8) * K_ + k0 + scolx,
                  (char*)&Bs[buf][0] + seg * 1024);
        }
    };

    stage(0, 0);
    __syncthreads();
    int cur = 0;
    for (int k0 = 0; k0 < K_; k0 += 64) {
        if (k0 + 64 < K_) stage(cur ^ 1, k0 + 64);   // issue next tile FIRST
        #pragma unroll
        for (int kk = 0; kk < 2; ++kk) {
            bf16x8 af[4], bfr[NF];
            #pragma unroll
            for (int mi = 0; mi < 4; ++mi) {
                const int row = wm + mi * 16 + c;
                const int sc = (kk * 64 + u * 16) ^ ((row & 7) << 4);
                af[mi] = *(const bf16x8*)((char*)&As[cur][0] + row * 128 + sc);
            }
            #pragma unroll
            for (int ni = 0; ni < NF; ++ni) {
                const int row = wn + ni * 16 + c;
                const int sc = (kk * 64 + u * 16) ^ ((row & 7) << 4);
                bfr[ni] = *(const bf16x8*)((char*)&Bs[cur][0] + row * 128 + sc);
            }
            #pragma unroll
            for (int mi = 0; mi < 4; ++mi)
                #pragma unroll
                for (int ni = 0; ni < NF; ++ni)
                    acc[mi][ni] = __builtin_amdgcn_mfma_f32_16x16x32_bf16(
                        af[mi], bfr[ni], acc[mi][ni], 0, 0, 0);
        }
        __syncthreads();               // drains next-tile loads + orders buf reads
        cur ^= 1;
    }

    if constexpr (TYPE == 1) {
        #pragma unroll
        for (int mi = 0; mi < 4; ++mi)
            #pragma unroll
            for (int ni = 0; ni < NF; ++ni)
                #pragma unroll
                for (int r = 0; r < 4; ++r)
                    fout[(size_t)(bm + wm + 16*mi + 4*u + r) * HID_ + (bn + wn + 16*ni + c)] =
                        acc[mi][ni][r];
    } else {
        const int sec = bn >> 10;
        const int h = ((bn + wn) & 1023) >> 6;
        if (sec == 2) {
            #pragma unroll
            for (int mi = 0; mi < 4; ++mi)
                #pragma unroll
                for (int r = 0; r < 4; ++r) {
                    const int mg = bm + wm + 16*mi + 4*u + r;
                    const int bb = mg >> 11, t = mg & 2047;
                    const int tk = (t & ~12) | ((t & 4) << 1) | ((t & 8) >> 1);  // kappa
                    #pragma unroll
                    for (int ni = 0; ni < 4; ++ni)
                        vtb[((size_t)(bb*16 + h) * 64 + 16*ni + c) * 2048 + tk] =
                            f2bf(acc[mi][ni][r]);
                }
        } else {
            unsigned short* ob = sec ? kb : qb;
            const float qsc = sec ? 1.0f : (0.125f * LOG2E);   // q in log2 domain
            #pragma unroll
            for (int mi = 0; mi < 4; ++mi)
                #pragma unroll
                for (int r = 0; r < 4; ++r) {
                    const int mg = bm + wm + 16*mi + 4*u + r;
                    const int bb = mg >> 11, t = mg & 2047;
                    const size_t base = ((size_t)(bb*16 + h) * 2048 + t) * 64;
                    #pragma unroll
                    for (int ni = 0; ni < 2; ++ni) {
                        const int dlo = 16*ni + c;
                        const float cv = cs[t*64 + dlo], sv = sn[t*64 + dlo];
                        const float Aa = acc[mi][ni][r], Bb = acc[mi][ni+2][r];
                        ob[base + dlo]      = f2bf((Aa*cv - Bb*sv) * qsc);
                        ob[base + dlo + 32] = f2bf((Bb*cv + Aa*sv) * qsc);
                    }
                }
        }
    }
}

// ---------------- attn18 (unchanged; best measured 52.0us) ----------------
__global__ __launch_bounds__(256)
void attn18(const unsigned short* __restrict__ q, const unsigned short* __restrict__ k,
            const unsigned short* __restrict__ vt, unsigned short* __restrict__ ab) {
    const int raw = blockIdx.x;                          // 512 = 32 bh x 16 chunks
    const int bh     = (raw & 7) + 8 * ((raw >> 3) & 3); // same-bh -> same XCD
    const int qchunk = 15 - (raw >> 5);                  // heavy blocks first
    const int tid = threadIdx.x;
    const int wid = tid >> 6, lane = tid & 63;
    const int h = lane >> 5, c = lane & 31;
    const int b = bh >> 4, hh = bh & 15;
    const int q0 = qchunk * 128;
    const int qgcA = q0 + c, qgcB = q0 + 32 + c, qgcC = q0 + 64 + c, qgcD = q0 + 96 + c;
    const int stAd = 4 * qchunk;                         // tile diag subtiles
    const int stBd = stAd + 1, stCd = stAd + 2, stDd = stAd + 3;
    const int NT   = stAd + 4;
    const unsigned short* qp = q  + (size_t)bh * (T_*64);
    const unsigned short* kp = k  + (size_t)bh * (T_*64);
    const unsigned short* vp = vt + (size_t)bh * (64*T_);

    const int kloff  = c * 64 + 8 * h;
    const int vloff0 = c * 2048 + 8 * h;
    const int vloff1 = vloff0 + 32 * 2048;

    bf16x8 qfA[4], qfB[4], qfC[4], qfD[4];
    {
        const unsigned short* qrowA = qp + (q0 + c) * 64 + 8 * h;
        #pragma unroll
        for (int s = 0; s < 4; ++s) {
            qfA[s] = *(const bf16x8*)(qrowA + s * 16);
            qfB[s] = *(const bf16x8*)(qrowA + 32 * 64 + s * 16);
            qfC[s] = *(const bf16x8*)(qrowA + 64 * 64 + s * 16);
            qfD[s] = *(const bf16x8*)(qrowA + 96 * 64 + s * 16);
        }
    }

    f32x16 OA0 = {}, OA1 = {}, OB0 = {}, OB1 = {};
    f32x16 OC0 = {}, OC1 = {}, OD0 = {}, OD1 = {};
    float mA = -1e30f, lA = 0.f, mB = -1e30f, lB = 0.f;
    float mC = -1e30f, lC = 0.f, mD = -1e30f, lD = 0.f;

    auto loadK = [&](bf16x8 (&kf)[4], int st) {
        const unsigned short* kst = kp + (st << 11);
        #pragma unroll
        for (int s = 0; s < 4; ++s)
            kf[s] = *(const bf16x8*)(kst + kloff + s * 16);
    };

    auto tileRest = [&](f32x16 sa, int st, int std_, int qgc,
                        float& m, float& l, f32x16& O0, f32x16& O1,
                        const bf16x8& vf0, const bf16x8& vf1,
                        const bf16x8& vf2, const bf16x8& vf3) {
        const int kvs = st << 5;
        float p[16];
        #pragma unroll
        for (int r = 0; r < 16; ++r) p[r] = sa[r];
        if (st == std_) {                        // diagonal subtile only
            #pragma unroll
            for (int r = 0; r < 16; ++r) {
                const int kk = kvs + (r & 3) + 8 * (r >> 2) + 4 * h;
                if (kk > qgc) p[r] = -1e30f;
            }
        }
        const float a0 = fmaxf(fmaxf(p[0],  p[1]),  p[2]);
        const float a1 = fmaxf(fmaxf(p[3],  p[4]),  p[5]);
        const float a2 = fmaxf(fmaxf(p[6],  p[7]),  p[8]);
        const float a3 = fmaxf(fmaxf(p[9],  p[10]), p[11]);
        const float a4 = fmaxf(fmaxf(p[12], p[13]), p[14]);
        float mx = fmaxf(fmaxf(fmaxf(a0, a1), fmaxf(a2, a3)), fmaxf(a4, p[15]));
        if (!__all(mx <= m + 8.0f)) {            // defer-max (log2 domain)
            mx = fmaxf(mx, __shfl_xor(mx, 32));
            const float mn = fmaxf(m, mx);
            const float f = __builtin_amdgcn_exp2f(m - mn);
            m = mn; l *= f;
            #pragma unroll
            for (int r = 0; r < 16; ++r) { O0[r] *= f; O1[r] *= f; }
        }
        float ps = 0.f;
        #pragma unroll
        for (int r = 0; r < 16; ++r) {
            p[r] = __builtin_amdgcn_exp2f(p[r] - m);
            ps += p[r];
        }
        l += ps;
        u32x4 B0w = { pkt(p[0],  p[1]),  pkt(p[2],  p[3]),
                      pkt(p[4],  p[5]),  pkt(p[6],  p[7])  };
        u32x4 B1w = { pkt(p[8],  p[9]),  pkt(p[10], p[11]),
                      pkt(p[12], p[13]), pkt(p[14], p[15]) };
        bf16x8 PB0 = __builtin_bit_cast(bf16x8, B0w);
        bf16x8 PB1 = __builtin_bit_cast(bf16x8, B1w);
        __builtin_amdgcn_s_setprio(1);
        O0 = __builtin_amdgcn_mfma_f32_32x32x16_bf16(vf0, PB0, O0, 0, 0, 0);
        O0 = __builtin_amdgcn_mfma_f32_32x32x16_bf16(vf1, PB1, O0, 0, 0, 0);
        O1 = __builtin_amdgcn_mfma_f32_32x32x16_bf16(vf2, PB0, O1, 0, 0, 0);
        O1 = __builtin_amdgcn_mfma_f32_32x32x16_bf16(vf3, PB1, O1, 0, 0, 0);
        __builtin_amdgcn_s_setprio(0);
    };

    auto qkt = [&](const bf16x8 (&kf)[4], const bf16x8 (&qf)[4]) -> f32x16 {
        __builtin_amdgcn_s_setprio(1);
        f32x16 sa = {};
        #pragma unroll
        for (int s = 0; s < 4; ++s)
            sa = __builtin_amdgcn_mfma_f32_32x32x16_bf16(kf[s], qf[s], sa, 0, 0, 0);
        __builtin_amdgcn_s_setprio(0);
        return sa;
    };

    bf16x8 kf_[4];
    if (wid < NT) {
        loadK(kf_, wid);
        for (int st = wid; st < NT; st += 4) {
            const unsigned short* vst = vp + (st << 5);
            bf16x8 vf0 = *(const bf16x8*)(vst + vloff0);
            bf16x8 vf1 = *(const bf16x8*)(vst + vloff0 + 16);
            bf16x8 vf2 = *(const bf16x8*)(vst + vloff1);
            bf16x8 vf3 = *(const bf16x8*)(vst + vloff1 + 16);
            const bool doA = (st <= stAd);
            const bool doB = (st <= stBd);
            const bool doC = (st <= stCd);
            if (doA) {
                f32x16 sa = qkt(kf_, qfA);
                tileRest(sa, st, stAd, qgcA, mA, lA, OA0, OA1, vf0, vf1, vf2, vf3);
            }
            if (doB) {
                f32x16 sa = qkt(kf_, qfB);
                tileRest(sa, st, stBd, qgcB, mB, lB, OB0, OB1, vf0, vf1, vf2, vf3);
            }
            if (doC) {
                f32x16 sa = qkt(kf_, qfC);
                tileRest(sa, st, stCd, qgcC, mC, lC, OC0, OC1, vf0, vf1, vf2, vf3);
            }
            {
                f32x16 sa = qkt(kf_, qfD);
                if (st + 4 < NT) loadK(kf_, st + 4);     // D is last kf read
                tileRest(sa, st, stDd, qgcD, mD, lD, OD0, OD1, vf0, vf1, vf2, vf3);
            }
        }
    }
    lA += __shfl_xor(lA, 32);
    lB += __shfl_xor(lB, 32);
    lC += __shfl_xor(lC, 32);
    lD += __shfl_xor(lD, 32);

    // ---- merge the 4 wave-partials in LDS (bf16-packed, stride 34 u32) ----
    __shared__ unsigned OSu[4][128 * 34];
    __shared__ float mS[4][128], lS[4][128];
    if (h == 0) {
        mS[wid][c] = mA;      lS[wid][c] = lA;
        mS[wid][32 + c] = mB; lS[wid][32 + c] = lB;
        mS[wid][64 + c] = mC; lS[wid][64 + c] = lC;
        mS[wid][96 + c] = mD; lS[wid][96 + c] = lD;
    }
    {
        unsigned* os = &OSu[wid][0];
        const int rbA = c * 34 + 2 * h;
        const int rbB = (32 + c) * 34 + 2 * h;
        const int rbC = (64 + c) * 34 + 2 * h;
        const int rbD = (96 + c) * 34 + 2 * h;
        #pragma unroll
        for (int j = 0; j < 4; ++j) {
            os[rbA + 4*j]          = pk2(OA0[4*j],   OA0[4*j+1]);
            os[rbA + 4*j + 1]      = pk2(OA0[4*j+2], OA0[4*j+3]);
            os[rbA + 16 + 4*j]     = pk2(OA1[4*j],   OA1[4*j+1]);
            os[rbA + 16 + 4*j + 1] = pk2(OA1[4*j+2], OA1[4*j+3]);
            os[rbB + 4*j]          = pk2(OB0[4*j],   OB0[4*j+1]);
            os[rbB + 4*j + 1]      = pk2(OB0[4*j+2], OB0[4*j+3]);
            os[rbB + 16 + 4*j]     = pk2(OB1[4*j],   OB1[4*j+1]);
            os[rbB + 16 + 4*j + 1] = pk2(OB1[4*j+2], OB1[4*j+3]);
            os[rbC + 4*j]          = pk2(OC0[4*j],   OC0[4*j+1]);
            os[rbC + 4*j + 1]      = pk2(OC0[4*j+2], OC0[4*j+3]);
            os[rbC + 16 + 4*j]     = pk2(OC1[4*j],   OC1[4*j+1]);
            os[rbC + 16 + 4*j + 1] = pk2(OC1[4*j+2], OC1[4*j+3]);
            os[rbD + 4*j]          = pk2(OD0[4*j],   OD0[4*j+1]);
            os[rbD + 4*j + 1]      = pk2(OD0[4*j+2], OD0[4*j+3]);
            os[rbD + 16 + 4*j]     = pk2(OD1[4*j],   OD1[4*j+1]);
            os[rbD + 16 + 4*j + 1] = pk2(OD1[4*j+2], OD1[4*j+3]);
        }
    }
    __syncthreads();

    // 4 passes of 32 rows; each thread handles 4 u32 = 8 d
    #pragma unroll
    for (int rr = 0; rr < 4; ++rr) {
        const int rl = rr * 32 + (tid & 31);
        const int ug = (tid >> 5) * 4;               // 0,4,...,28
        const float M = fmaxf(fmaxf(mS[0][rl], mS[1][rl]), fmaxf(mS[2][rl], mS[3][rl]));
        float acc[8] = {};
        float L = 0.f;
        #pragma unroll
        for (int w2 = 0; w2 < 4; ++w2) {
            const float sc = __builtin_amdgcn_exp2f(mS[w2][rl] - M);
            L += lS[w2][rl] * sc;
            u32x4 pa = *(u32x4*)&OSu[w2][rl * 34 + ug];
            #pragma unroll
            for (int t = 0; t < 4; ++t) {
                acc[2*t]   += __builtin_bit_cast(float, pa[t] << 16) * sc;
                acc[2*t+1] += __builtin_bit_cast(float, pa[t] & 0xffff0000u) * sc;
            }
        }
        const float inv = 1.0f / L;
        uint4 ov;
        ov.x = pk2(acc[0]*inv, acc[1]*inv);
        ov.y = pk2(acc[2]*inv, acc[3]*inv);
        ov.z = pk2(acc[4]*inv, acc[5]*inv);
        ov.w = pk2(acc[6]*inv, acc[7]*inv);
        *(uint4*)(ab + ((size_t)(b * T_) + q0 + rl) * HID_ + hh * 64 + ug * 2) = ov;
    }
}

extern "C" void kernel_launch(void* const* d_in, const int* in_sizes, int n_in,
                              void* d_out, int out_size, void* d_ws, size_t ws_size,
                              hipStream_t stream) {
    const float* x  = (const float*)d_in[0];
    const float* Wq = (const float*)d_in[1];
    const float* Wk = (const float*)d_in[2];
    const float* Wv = (const float*)d_in[3];
    const float* Wo = (const float*)d_in[4];
    const float* cs = (const float*)d_in[5];
    const float* sn = (const float*)d_in[6];
    char* wsb = (char*)d_ws;
    unsigned short* xb  = (unsigned short*)(wsb);                  // 8 MB
    unsigned short* wqb = (unsigned short*)(wsb + (8u  << 20));    // 2 MB each
    unsigned short* wkb = (unsigned short*)(wsb + (10u << 20));
    unsigned short* wvb = (unsigned short*)(wsb + (12u << 20));
    unsigned short* wob = (unsigned short*)(wsb + (14u << 20));
    unsigned short* qb  = (unsigned short*)(wsb + (16u << 20));
    unsigned short* kb  = (unsigned short*)(wsb + (24u << 20));
    unsigned short* vtb = (unsigned short*)(wsb + (32u << 20));
    unsigned short* ab  = (unsigned short*)(wsb + (40u << 20));

    cast_all<<<4096, 256, 0, stream>>>(x, Wq, Wk, Wv, Wo, xb, wqb, wkb, wvb, wob);

    gemm_k<0><<<768, 256, 0, stream>>>(
        xb, wqb, wkb, wvb, cs, sn, qb, kb, vtb, nullptr);
    attn18<<<512, 256, 0, stream>>>(qb, kb, vtb, ab);
    gemm_k<1><<<512, 256, 0, stream>>>(
        ab, wob, nullptr, nullptr, nullptr, nullptr,
        nullptr, nullptr, nullptr, (float*)d_out);
}

// Round 26
// 108.161 us; speedup vs baseline: 1.1356x; 1.1356x over previous
//
#include <hip/hip_runtime.h>
#include <hip/hip_bf16.h>

#define B_   2
#define T_   2048
#define HID_ 1024
#define NH_  16
#define HD_  64
#define K_   1024
#define M_   (B_*T_)

typedef __attribute__((ext_vector_type(8)))  short bf16x8;
typedef __attribute__((ext_vector_type(4)))  float f32x4;
typedef __attribute__((ext_vector_type(16))) float f32x16;
typedef __attribute__((ext_vector_type(4)))  unsigned int u32x4;
typedef __attribute__((ext_vector_type(2)))  unsigned int u32x2;

#define LOG2E 1.44269504088896340736f

__device__ inline unsigned short f2bf(float f) {
    __hip_bfloat16 h = __float2bfloat16(f);
    return __builtin_bit_cast(unsigned short, h);
}
__device__ inline unsigned int pk2(float a, float b) {
    return (unsigned int)f2bf(a) | ((unsigned int)f2bf(b) << 16);
}
// truncation pack: (a>>16) | (b & 0xffff0000) in ONE v_perm_b32
__device__ inline unsigned int pkt(float a, float b) {
    return __builtin_amdgcn_perm(__builtin_bit_cast(unsigned, a),
                                 __builtin_bit_cast(unsigned, b), 0x03020706u);
}
__device__ inline bf16x8 cvt8(float4 a, float4 b) {
    bf16x8 r;
    r[0]=(short)f2bf(a.x); r[1]=(short)f2bf(a.y); r[2]=(short)f2bf(a.z); r[3]=(short)f2bf(a.w);
    r[4]=(short)f2bf(b.x); r[5]=(short)f2bf(b.y); r[6]=(short)f2bf(b.z); r[7]=(short)f2bf(b.w);
    return r;
}

// ---------------- fp32 -> bf16 cast, single launch (x + 4 weights) ----------------
__global__ __launch_bounds__(256)
void cast_all(const float* __restrict__ x,
              const float* __restrict__ W0, const float* __restrict__ W1,
              const float* __restrict__ W2, const float* __restrict__ W3,
              unsigned short* __restrict__ xo,
              unsigned short* __restrict__ o0, unsigned short* __restrict__ o1,
              unsigned short* __restrict__ o2, unsigned short* __restrict__ o3) {
    const int blk = blockIdx.x;
    const float* in;
    unsigned short* out;
    int i;
    if (blk < 2048) {
        in = x; out = xo; i = blk * 256 + threadIdx.x;
    } else {
        const int wb = blk - 2048, sec = wb >> 9;
        in  = (sec == 0) ? W0 : (sec == 1) ? W1 : (sec == 2) ? W2 : W3;
        out = (sec == 0) ? o0 : (sec == 1) ? o1 : (sec == 2) ? o2 : o3;
        i = (wb & 511) * 256 + threadIdx.x;
    }
    float4 a = ((const float4*)in)[2*i], b = ((const float4*)in)[2*i + 1];
    ((bf16x8*)out)[i] = cvt8(a, b);
}

// ---------------- bf16 GEMM-NT: reg-staged + XOR-swizzled LDS (proven best) ----------
// Third gload_lds attempt (R25) regressed: 2x-dbuf LDS = 128KB -> 1 block/CU.
// This reg-staged kernel keeps 32KB LDS (3 blocks/CU), zero bank conflicts.
template<int TYPE>
__global__ __launch_bounds__(256)
void gemm_k(const unsigned short* __restrict__ A, const unsigned short* __restrict__ W0,
            const unsigned short* __restrict__ W1, const unsigned short* __restrict__ W2,
            const float* __restrict__ cs, const float* __restrict__ sn,
            unsigned short* __restrict__ qb, unsigned short* __restrict__ kb,
            unsigned short* __restrict__ vtb, float* __restrict__ fout) {
    constexpr int BN = (TYPE == 1) ? 64 : 128;
    constexpr int NB = BN / 32;
    constexpr int NF = BN / 32;
    __shared__ unsigned short As[128*64];
    __shared__ unsigned short Bs[BN*64];
    const int tid = threadIdx.x;
    const int w = tid >> 6, lane = tid & 63;
    const int u = lane >> 4, c = lane & 15;
    const int bid = blockIdx.x;
    const int xcd = bid & 7, idx = bid >> 3;
    int bmi, bni;
    if constexpr (TYPE == 0) {
        bmi = (xcd & 3) * 8 + (idx & 7);
        bni = (xcd >> 2) * 12 + (idx >> 3);
    } else {
        bmi = (xcd & 3) * 8 + (idx & 7);
        bni = (xcd >> 2) * 8 + (idx >> 3);
    }
    const int bm = bmi * 128, bn = bni * BN;
    const int wm = (w & 1) * 64, wn = (w >> 1) * (BN / 2);
    const int srow = tid >> 3, scol = (tid & 7) << 3;

    const unsigned short* Wsec;
    int wrowbase;
    if constexpr (TYPE == 0) {
        const int sec = bn >> 10;
        Wsec = (sec == 0) ? W0 : ((sec == 1) ? W1 : W2);
        wrowbase = bn & 1023;
    } else {
        Wsec = W0;
        wrowbase = bn;
    }
    const unsigned short* Wp = Wsec + (size_t)(wrowbase + srow) * K_ + scol;
    const unsigned short* Ap = A + (size_t)(bm + srow) * K_ + scol;

    f32x4 acc[4][NF] = {};
    bf16x8 ra[4], rb[NB];

    auto loadin = [&](int k0) {
        #pragma unroll
        for (int i = 0; i < 4; ++i)
            ra[i] = *(const bf16x8*)(Ap + (size_t)i * 32 * K_ + k0);
        #pragma unroll
        for (int i = 0; i < NB; ++i)
            rb[i] = *(const bf16x8*)(Wp + (size_t)i * 32 * K_ + k0);
    };
    loadin(0);

    for (int k0 = 0; k0 < K_; k0 += 64) {
        __syncthreads();
        #pragma unroll
        for (int i = 0; i < 4; ++i) {
            const int row = i * 32 + srow;
            const int sc = (scol * 2) ^ ((row & 7) << 4);
            *(bf16x8*)((char*)As + row * 128 + sc) = ra[i];
        }
        #pragma unroll
        for (int i = 0; i < NB; ++i) {
            const int row = i * 32 + srow;
            const int sc = (scol * 2) ^ ((row & 7) << 4);
            *(bf16x8*)((char*)Bs + row * 128 + sc) = rb[i];
        }
        __syncthreads();
        if (k0 < K_ - 64) loadin(k0 + 64);
        #pragma unroll
        for (int kk = 0; kk < 2; ++kk) {
            bf16x8 af[4], bfr[NF];
            #pragma unroll
            for (int mi = 0; mi < 4; ++mi) {
                const int row = wm + mi * 16 + c;
                const int sc = (kk * 64 + u * 16) ^ ((row & 7) << 4);
                af[mi] = *(const bf16x8*)((char*)As + row * 128 + sc);
            }
            #pragma unroll
            for (int ni = 0; ni < NF; ++ni) {
                const int row = wn + ni * 16 + c;
                const int sc = (kk * 64 + u * 16) ^ ((row & 7) << 4);
                bfr[ni] = *(const bf16x8*)((char*)Bs + row * 128 + sc);
            }
            #pragma unroll
            for (int mi = 0; mi < 4; ++mi)
                #pragma unroll
                for (int ni = 0; ni < NF; ++ni)
                    acc[mi][ni] = __builtin_amdgcn_mfma_f32_16x16x32_bf16(
                        af[mi], bfr[ni], acc[mi][ni], 0, 0, 0);
        }
    }

    if constexpr (TYPE == 1) {
        #pragma unroll
        for (int mi = 0; mi < 4; ++mi)
            #pragma unroll
            for (int ni = 0; ni < NF; ++ni)
                #pragma unroll
                for (int r = 0; r < 4; ++r)
                    fout[(size_t)(bm + wm + 16*mi + 4*u + r) * HID_ + (bn + wn + 16*ni + c)] =
                        acc[mi][ni][r];
    } else {
        const int sec = bn >> 10;
        const int h = ((bn + wn) & 1023) >> 6;
        if (sec == 2) {
            #pragma unroll
            for (int mi = 0; mi < 4; ++mi)
                #pragma unroll
                for (int r = 0; r < 4; ++r) {
                    const int mg = bm + wm + 16*mi + 4*u + r;
                    const int bb = mg >> 11, t = mg & 2047;
                    const int tk = (t & ~12) | ((t & 4) << 1) | ((t & 8) >> 1);  // kappa
                    #pragma unroll
                    for (int ni = 0; ni < 4; ++ni)
                        vtb[((size_t)(bb*16 + h) * 64 + 16*ni + c) * 2048 + tk] =
                            f2bf(acc[mi][ni][r]);
                }
        } else {
            unsigned short* ob = sec ? kb : qb;
            const float qsc = sec ? 1.0f : (0.125f * LOG2E);   // q in log2 domain
            #pragma unroll
            for (int mi = 0; mi < 4; ++mi)
                #pragma unroll
                for (int r = 0; r < 4; ++r) {
                    const int mg = bm + wm + 16*mi + 4*u + r;
                    const int bb = mg >> 11, t = mg & 2047;
                    const size_t base = ((size_t)(bb*16 + h) * 2048 + t) * 64;
                    #pragma unroll
                    for (int ni = 0; ni < 2; ++ni) {
                        const int dlo = 16*ni + c;
                        const float cv = cs[t*64 + dlo], sv = sn[t*64 + dlo];
                        const float Aa = acc[mi][ni][r], Bb = acc[mi][ni+2][r];
                        ob[base + dlo]      = f2bf((Aa*cv - Bb*sv) * qsc);
                        ob[base + dlo + 32] = f2bf((Bb*cv + Aa*sv) * qsc);
                    }
                }
        }
    }
}

// ---------------- attn18: 128 q rows per wave (4 q-tiles), shared K/V ----------------
__global__ __launch_bounds__(256)
void attn18(const unsigned short* __restrict__ q, const unsigned short* __restrict__ k,
            const unsigned short* __restrict__ vt, unsigned short* __restrict__ ab) {
    const int raw = blockIdx.x;                          // 512 = 32 bh x 16 chunks
    const int bh     = (raw & 7) + 8 * ((raw >> 3) & 3); // same-bh -> same XCD
    const int qchunk = 15 - (raw >> 5);                  // heavy blocks first
    const int tid = threadIdx.x;
    const int wid = tid >> 6, lane = tid & 63;
    const int h = lane >> 5, c = lane & 31;
    const int b = bh >> 4, hh = bh & 15;
    const int q0 = qchunk * 128;
    const int qgcA = q0 + c, qgcB = q0 + 32 + c, qgcC = q0 + 64 + c, qgcD = q0 + 96 + c;
    const int stAd = 4 * qchunk;                         // tile diag subtiles
    const int stBd = stAd + 1, stCd = stAd + 2, stDd = stAd + 3;
    const int NT   = stAd + 4;
    const unsigned short* qp = q  + (size_t)bh * (T_*64);
    const unsigned short* kp = k  + (size_t)bh * (T_*64);
    const unsigned short* vp = vt + (size_t)bh * (64*T_);

    const int kloff  = c * 64 + 8 * h;
    const int vloff0 = c * 2048 + 8 * h;
    const int vloff1 = vloff0 + 32 * 2048;

    bf16x8 qfA[4], qfB[4], qfC[4], qfD[4];
    {
        const unsigned short* qrowA = qp + (q0 + c) * 64 + 8 * h;
        #pragma unroll
        for (int s = 0; s < 4; ++s) {
            qfA[s] = *(const bf16x8*)(qrowA + s * 16);
            qfB[s] = *(const bf16x8*)(qrowA + 32 * 64 + s * 16);
            qfC[s] = *(const bf16x8*)(qrowA + 64 * 64 + s * 16);
            qfD[s] = *(const bf16x8*)(qrowA + 96 * 64 + s * 16);
        }
    }

    f32x16 OA0 = {}, OA1 = {}, OB0 = {}, OB1 = {};
    f32x16 OC0 = {}, OC1 = {}, OD0 = {}, OD1 = {};
    float mA = -1e30f, lA = 0.f, mB = -1e30f, lB = 0.f;
    float mC = -1e30f, lC = 0.f, mD = -1e30f, lD = 0.f;

    auto loadK = [&](bf16x8 (&kf)[4], int st) {
        const unsigned short* kst = kp + (st << 11);
        #pragma unroll
        for (int s = 0; s < 4; ++s)
            kf[s] = *(const bf16x8*)(kst + kloff + s * 16);
    };

    auto tileRest = [&](f32x16 sa, int st, int std_, int qgc,
                        float& m, float& l, f32x16& O0, f32x16& O1,
                        const bf16x8& vf0, const bf16x8& vf1,
                        const bf16x8& vf2, const bf16x8& vf3) {
        const int kvs = st << 5;
        float p[16];
        #pragma unroll
        for (int r = 0; r < 16; ++r) p[r] = sa[r];
        if (st == std_) {                        // diagonal subtile only
            #pragma unroll
            for (int r = 0; r < 16; ++r) {
                const int kk = kvs + (r & 3) + 8 * (r >> 2) + 4 * h;
                if (kk > qgc) p[r] = -1e30f;
            }
        }
        const float a0 = fmaxf(fmaxf(p[0],  p[1]),  p[2]);
        const float a1 = fmaxf(fmaxf(p[3],  p[4]),  p[5]);
        const float a2 = fmaxf(fmaxf(p[6],  p[7]),  p[8]);
        const float a3 = fmaxf(fmaxf(p[9],  p[10]), p[11]);
        const float a4 = fmaxf(fmaxf(p[12], p[13]), p[14]);
        float mx = fmaxf(fmaxf(fmaxf(a0, a1), fmaxf(a2, a3)), fmaxf(a4, p[15]));
        if (!__all(mx <= m + 8.0f)) {            // defer-max (log2 domain)
            mx = fmaxf(mx, __shfl_xor(mx, 32));
            const float mn = fmaxf(m, mx);
            const float f = __builtin_amdgcn_exp2f(m - mn);
            m = mn; l *= f;
            #pragma unroll
            for (int r = 0; r < 16; ++r) { O0[r] *= f; O1[r] *= f; }
        }
        float ps = 0.f;
        #pragma unroll
        for (int r = 0; r < 16; ++r) {
            p[r] = __builtin_amdgcn_exp2f(p[r] - m);
            ps += p[r];
        }
        l += ps;
        u32x4 B0w = { pkt(p[0],  p[1]),  pkt(p[2],  p[3]),
                      pkt(p[4],  p[5]),  pkt(p[6],  p[7])  };
        u32x4 B1w = { pkt(p[8],  p[9]),  pkt(p[10], p[11]),
                      pkt(p[12], p[13]), pkt(p[14], p[15]) };
        bf16x8 PB0 = __builtin_bit_cast(bf16x8, B0w);
        bf16x8 PB1 = __builtin_bit_cast(bf16x8, B1w);
        __builtin_amdgcn_s_setprio(1);
        O0 = __builtin_amdgcn_mfma_f32_32x32x16_bf16(vf0, PB0, O0, 0, 0, 0);
        O0 = __builtin_amdgcn_mfma_f32_32x32x16_bf16(vf1, PB1, O0, 0, 0, 0);
        O1 = __builtin_amdgcn_mfma_f32_32x32x16_bf16(vf2, PB0, O1, 0, 0, 0);
        O1 = __builtin_amdgcn_mfma_f32_32x32x16_bf16(vf3, PB1, O1, 0, 0, 0);
        __builtin_amdgcn_s_setprio(0);
    };

    auto qkt = [&](const bf16x8 (&kf)[4], const bf16x8 (&qf)[4]) -> f32x16 {
        __builtin_amdgcn_s_setprio(1);
        f32x16 sa = {};
        #pragma unroll
        for (int s = 0; s < 4; ++s)
            sa = __builtin_amdgcn_mfma_f32_32x32x16_bf16(kf[s], qf[s], sa, 0, 0, 0);
        __builtin_amdgcn_s_setprio(0);
        return sa;
    };

    bf16x8 kf_[4];
    if (wid < NT) {
        loadK(kf_, wid);
        for (int st = wid; st < NT; st += 4) {
            const unsigned short* vst = vp + (st << 5);
            bf16x8 vf0 = *(const bf16x8*)(vst + vloff0);
            bf16x8 vf1 = *(const bf16x8*)(vst + vloff0 + 16);
            bf16x8 vf2 = *(const bf16x8*)(vst + vloff1);
            bf16x8 vf3 = *(const bf16x8*)(vst + vloff1 + 16);
            const bool doA = (st <= stAd);
            const bool doB = (st <= stBd);
            const bool doC = (st <= stCd);
            if (doA) {
                f32x16 sa = qkt(kf_, qfA);
                tileRest(sa, st, stAd, qgcA, mA, lA, OA0, OA1, vf0, vf1, vf2, vf3);
            }
            if (doB) {
                f32x16 sa = qkt(kf_, qfB);
                tileRest(sa, st, stBd, qgcB, mB, lB, OB0, OB1, vf0, vf1, vf2, vf3);
            }
            if (doC) {
                f32x16 sa = qkt(kf_, qfC);
                tileRest(sa, st, stCd, qgcC, mC, lC, OC0, OC1, vf0, vf1, vf2, vf3);
            }
            {
                f32x16 sa = qkt(kf_, qfD);
                if (st + 4 < NT) loadK(kf_, st + 4);     // D is last kf read
                tileRest(sa, st, stDd, qgcD, mD, lD, OD0, OD1, vf0, vf1, vf2, vf3);
            }
        }
    }
    lA += __shfl_xor(lA, 32);
    lB += __shfl_xor(lB, 32);
    lC += __shfl_xor(lC, 32);
    lD += __shfl_xor(lD, 32);

    // ---- merge the 4 wave-partials in LDS (bf16-packed, stride 34 u32) ----
    __shared__ unsigned OSu[4][128 * 34];
    __shared__ float mS[4][128], lS[4][128];
    if (h == 0) {
        mS[wid][c] = mA;      lS[wid][c] = lA;
        mS[wid][32 + c] = mB; lS[wid][32 + c] = lB;
        mS[wid][64 + c] = mC; lS[wid][64 + c] = lC;
        mS[wid][96 + c] = mD; lS[wid][96 + c] = lD;
    }
    {
        unsigned* os = &OSu[wid][0];
        const int rbA = c * 34 + 2 * h;
        const int rbB = (32 + c) * 34 + 2 * h;
        const int rbC = (64 + c) * 34 + 2 * h;
        const int rbD = (96 + c) * 34 + 2 * h;
        #pragma unroll
        for (int j = 0; j < 4; ++j) {
            os[rbA + 4*j]          = pk2(OA0[4*j],   OA0[4*j+1]);
            os[rbA + 4*j + 1]      = pk2(OA0[4*j+2], OA0[4*j+3]);
            os[rbA + 16 + 4*j]     = pk2(OA1[4*j],   OA1[4*j+1]);
            os[rbA + 16 + 4*j + 1] = pk2(OA1[4*j+2], OA1[4*j+3]);
            os[rbB + 4*j]          = pk2(OB0[4*j],   OB0[4*j+1]);
            os[rbB + 4*j + 1]      = pk2(OB0[4*j+2], OB0[4*j+3]);
            os[rbB + 16 + 4*j]     = pk2(OB1[4*j],   OB1[4*j+1]);
            os[rbB + 16 + 4*j + 1] = pk2(OB1[4*j+2], OB1[4*j+3]);
            os[rbC + 4*j]          = pk2(OC0[4*j],   OC0[4*j+1]);
            os[rbC + 4*j + 1]      = pk2(OC0[4*j+2], OC0[4*j+3]);
            os[rbC + 16 + 4*j]     = pk2(OC1[4*j],   OC1[4*j+1]);
            os[rbC + 16 + 4*j + 1] = pk2(OC1[4*j+2], OC1[4*j+3]);
            os[rbD + 4*j]          = pk2(OD0[4*j],   OD0[4*j+1]);
            os[rbD + 4*j + 1]      = pk2(OD0[4*j+2], OD0[4*j+3]);
            os[rbD + 16 + 4*j]     = pk2(OD1[4*j],   OD1[4*j+1]);
            os[rbD + 16 + 4*j + 1] = pk2(OD1[4*j+2], OD1[4*j+3]);
        }
    }
    __syncthreads();

    // 4 passes of 32 rows; each thread handles 4 u32 = 8 d
    #pragma unroll
    for (int rr = 0; rr < 4; ++rr) {
        const int rl = rr * 32 + (tid & 31);
        const int ug = (tid >> 5) * 4;               // 0,4,...,28
        const float M = fmaxf(fmaxf(mS[0][rl], mS[1][rl]), fmaxf(mS[2][rl], mS[3][rl]));
        float acc[8] = {};
        float L = 0.f;
        #pragma unroll
        for (int w2 = 0; w2 < 4; ++w2) {
            const float sc = __builtin_amdgcn_exp2f(mS[w2][rl] - M);
            L += lS[w2][rl] * sc;
            u32x4 pa = *(u32x4*)&OSu[w2][rl * 34 + ug];
            #pragma unroll
            for (int t = 0; t < 4; ++t) {
                acc[2*t]   += __builtin_bit_cast(float, pa[t] << 16) * sc;
                acc[2*t+1] += __builtin_bit_cast(float, pa[t] & 0xffff0000u) * sc;
            }
        }
        const float inv = 1.0f / L;
        uint4 ov;
        ov.x = pk2(acc[0]*inv, acc[1]*inv);
        ov.y = pk2(acc[2]*inv, acc[3]*inv);
        ov.z = pk2(acc[4]*inv, acc[5]*inv);
        ov.w = pk2(acc[6]*inv, acc[7]*inv);
        *(uint4*)(ab + ((size_t)(b * T_) + q0 + rl) * HID_ + hh * 64 + ug * 2) = ov;
    }
}

extern "C" void kernel_launch(void* const* d_in, const int* in_sizes, int n_in,
                              void* d_out, int out_size, void* d_ws, size_t ws_size,
                              hipStream_t stream) {
    const float* x  = (const float*)d_in[0];
    const float* Wq = (const float*)d_in[1];
    const float* Wk = (const float*)d_in[2];
    const float* Wv = (const float*)d_in[3];
    const float* Wo = (const float*)d_in[4];
    const float* cs = (const float*)d_in[5];
    const float* sn = (const float*)d_in[6];
    char* wsb = (char*)d_ws;
    unsigned short* xb  = (unsigned short*)(wsb);                  // 8 MB
    unsigned short* wqb = (unsigned short*)(wsb + (8u  << 20));    // 2 MB each
    unsigned short* wkb = (unsigned short*)(wsb + (10u << 20));
    unsigned short* wvb = (unsigned short*)(wsb + (12u << 20));
    unsigned short* wob = (unsigned short*)(wsb + (14u << 20));
    unsigned short* qb  = (unsigned short*)(wsb + (16u << 20));
    unsigned short* kb  = (unsigned short*)(wsb + (24u << 20));
    unsigned short* vtb = (unsigned short*)(wsb + (32u << 20));
    unsigned short* ab  = (unsigned short*)(wsb + (40u << 20));

    cast_all<<<4096, 256, 0, stream>>>(x, Wq, Wk, Wv, Wo, xb, wqb, wkb, wvb, wob);

    gemm_k<0><<<768, 256, 0, stream>>>(
        xb, wqb, wkb, wvb, cs, sn, qb, kb, vtb, nullptr);
    attn18<<<512, 256, 0, stream>>>(qb, kb, vtb, ab);
    gemm_k<1><<<512, 256, 0, stream>>>(
        ab, wob, nullptr, nullptr, nullptr, nullptr,
        nullptr, nullptr, nullptr, (float*)d_out);
}